// Round 6
// baseline (1090.430 us; speedup 1.0000x reference)
//
#include <hip/hip_runtime.h>
#include <cstdint>
#include <cstddef>

typedef unsigned short u16;
typedef __attribute__((ext_vector_type(4))) float f32x4;
typedef __attribute__((ext_vector_type(8))) __bf16 bf16x8;
typedef __attribute__((ext_vector_type(8))) unsigned short u16x8;
typedef __attribute__((ext_vector_type(4))) unsigned short u16x4;

#define M_TOTAL 100352   // B*T*N = 8*64*196
#define K_DIM   384
#define QKV_N   1152
#define NHEADS  6
#define NPAT    196
#define SCL     0.125f   // HEAD_DIM^-0.5

__device__ __forceinline__ u16 f2bf(float f) {
    unsigned int u = __builtin_bit_cast(unsigned int, f);
    u += 0x7fffu + ((u >> 16) & 1u);   // RNE
    return (u16)(u >> 16);
}

// chunked XCD swizzle; requires gridDim.x % 8 == 0 (true for all launches here)
__device__ __forceinline__ int xcd_swz(int bid, int per_xcd) {
    return (bid & 7) * per_xcd + (bid >> 3);
}

// ---------------- fp32 -> bf16 convert (8 elems/thread) ----------------
__global__ void cvt_bf16_kern(const float* __restrict__ in, u16* __restrict__ out, int n8) {
    int i = blockIdx.x * 256 + threadIdx.x;
    if (i >= n8) return;
    const float4* p = (const float4*)in + (size_t)i * 2;
    float4 a = p[0], b = p[1];
    u16x8 o;
    o[0]=f2bf(a.x); o[1]=f2bf(a.y); o[2]=f2bf(a.z); o[3]=f2bf(a.w);
    o[4]=f2bf(b.x); o[5]=f2bf(b.y); o[6]=f2bf(b.z); o[7]=f2bf(b.w);
    *((u16x8*)out + i) = o;
}

// W_proj convert with column permute: out[o][h*64+d] = W[o][d*6+h]
__global__ void cvt_wproj_kern(const float* __restrict__ in, u16* __restrict__ out) {
    int i = blockIdx.x * 256 + threadIdx.x;   // i = o*384 + c''
    int o = i / 384;
    int c = i - o * 384;        // NOTE: 384 is not pow2 — cannot use i & 383
    int d = c & 63, h = c >> 6; // c'' = h*64 + d (64 IS pow2)
    out[i] = f2bf(in[(size_t)o * 384 + d * 6 + h]);
}

// ---------------- GEMM: C[M,NOUT] = A[M,384] * Bw[NOUT,384]^T + bias ----------------
// Round-6 structure: K=384 is small enough that each wave holds its A-strip's
// FULL K in 12 bf16x8 fragments (48 VGPR). So: NO LDS, NO barriers, NO staging.
// Block = 64 M-rows (4 waves x 16). Per wave: load 12 A-frags once (from fp32 x
// directly when AF32 — kills the separate cvt kernel), then loop 9 N-chunks of
// 128: 96 B-frag loads straight from global (B panels are L2-resident, reads are
// 16 rows x 64B fully-used lines) + 96 MFMA over 8 independent accumulators.
// Compiler is free to hoist B-loads arbitrarily far -- no barrier stops it.
template<int NOUT, bool BF16OUT, bool QSCALE, bool AF32>
__global__ __launch_bounds__(256, 3) void gemm_kern(
        const void* __restrict__ Ap, const u16* __restrict__ Bw,
        const float* __restrict__ bias, void* __restrict__ outp) {
    constexpr int NCH = NOUT / 128;
    constexpr int PER_XCD = (M_TOTAL / 64) / 8;   // 196
    int wg = xcd_swz(blockIdx.x, PER_XCD);
    int tid = threadIdx.x, l = tid & 63, w = tid >> 6;
    size_t row0 = (size_t)wg * 64 + w * 16;       // wave's 16-row strip
    int lr = l & 15, lg = l >> 4;

    // A fragments for full K: af[kk] covers k = kk*32 + lg*8 .. +8
    bf16x8 af[12];
    if constexpr (AF32) {
        const float* ar = (const float*)Ap + (row0 + lr) * K_DIM + lg * 8;
#pragma unroll
        for (int kk = 0; kk < 12; ++kk) {
            f32x4 lo = *(const f32x4*)(ar + kk * 32);
            f32x4 hi = *(const f32x4*)(ar + kk * 32 + 4);
            bf16x8 t;
            t[0]=(__bf16)lo[0]; t[1]=(__bf16)lo[1]; t[2]=(__bf16)lo[2]; t[3]=(__bf16)lo[3];
            t[4]=(__bf16)hi[0]; t[5]=(__bf16)hi[1]; t[6]=(__bf16)hi[2]; t[7]=(__bf16)hi[3];
            af[kk] = t;
        }
    } else {
        const u16* ar = (const u16*)Ap + (row0 + lr) * K_DIM + lg * 8;
#pragma unroll
        for (int kk = 0; kk < 12; ++kk)
            af[kk] = *(const bf16x8*)(ar + kk * 32);
    }

    for (int ch = 0; ch < NCH; ++ch) {
        int nbase = ch * 128;
        const u16* br = Bw + (size_t)(nbase + lr) * K_DIM + lg * 8;
        f32x4 acc[8] = {};
#pragma unroll
        for (int kk = 0; kk < 12; ++kk) {
#pragma unroll
            for (int nf = 0; nf < 8; ++nf) {
                bf16x8 b = *(const bf16x8*)(br + (size_t)nf * 16 * K_DIM + kk * 32);
                acc[nf] = __builtin_amdgcn_mfma_f32_16x16x32_bf16(af[kk], b, acc[nf], 0, 0, 0);
            }
        }
        // epilogue for this N-chunk
#pragma unroll
        for (int nf = 0; nf < 8; ++nf) {
            int col = nbase + nf * 16 + lr;
            float bv = bias[col];
#pragma unroll
            for (int r = 0; r < 4; ++r) {
                size_t row = row0 + lg * 4 + r;
                float v = acc[nf][r] + bv;
                if constexpr (QSCALE) { if (col < 384) v *= SCL; }
                if constexpr (BF16OUT)
                    ((u16*)outp)[row * NOUT + col] = f2bf(v);
                else
                    ((float*)outp)[row * NOUT + col] = v;
            }
        }
    }
}

// ---------------- attention per (b,t,h): 196x196 over head_dim 64 ----------------
// reads qkv[M,1152] (q pre-scaled), writes osc[M,384] at col h*64+d (h-major layout;
// the d*6+h reference permute is absorbed into the permuted W_proj)
__global__ __launch_bounds__(256, 2) void attn_kern(const u16* __restrict__ qkv,
                                                    u16* __restrict__ osc) {
    __shared__ u16 k_lds[208 * 72];   // [key][d], stride 72 (16B-aligned rows)
    __shared__ u16 vT[64 * 232];      // [d][key], keys zero-padded to 224+
    __shared__ u16 p_lds[4 * 16 * 36]; // per-wave P slice [16 q][32 keys], stride 36

    int wg = xcd_swz(blockIdx.x, 384);
    int h = wg % NHEADS;
    int bt = wg / NHEADS;
    size_t m_base = (size_t)bt * NPAT;
    int tid = threadIdx.x, l = tid & 63, w = tid >> 6;

    // stage K (rows 0..207; zero rows >=196). 8 lanes per row, coalesced 128B.
    {
        int d0 = (tid & 7) * 8;
#pragma unroll
        for (int it = 0; it < 7; ++it) {
            int n = it * 32 + (tid >> 3);
            if (n < 208) {
                u16x8 val = {};
                if (n < 196)
                    val = *(const u16x8*)(qkv + (m_base + n) * QKV_N + 384 + h * 64 + d0);
                *(u16x8*)&k_lds[n * 72 + d0] = val;
            }
        }
    }
    // stage V transposed: wave w owns d rows w*16..w*16+15; lane = key row.
    {
        int d0 = w * 16;
#pragma unroll
        for (int it = 0; it < 4; ++it) {
            int n = it * 64 + l;
            if (n < 232) {
                u16x8 v0 = {}, v1 = {};
                if (n < 196) {
                    const u16* src = qkv + (m_base + n) * QKV_N + 768 + h * 64 + d0;
                    v0 = *(const u16x8*)src;
                    v1 = *(const u16x8*)(src + 8);
                }
#pragma unroll
                for (int j = 0; j < 8; ++j) {
                    vT[(d0 + j) * 232 + n] = v0[j];
                    vT[(d0 + 8 + j) * 232 + n] = v1[j];
                }
            }
        }
    }
    __syncthreads();

    u16* pw = &p_lds[w * 16 * 36];
    for (int qt = w; qt < 13; qt += 4) {
        int q0 = qt * 16;
        // Q A-frags straight from global (q already scaled in qkv epilogue)
        int qrow = q0 + (l & 15); if (qrow > 195) qrow = 195;
        const u16* qsrc = qkv + (m_base + qrow) * QKV_N + h * 64 + (l >> 4) * 8;
        bf16x8 aq0 = *(const bf16x8*)qsrc;
        bf16x8 aq1 = *(const bf16x8*)(qsrc + 32);

        // S = q k^T : 13 key-frags
        f32x4 s[13];
#pragma unroll
        for (int f = 0; f < 13; ++f) {
            f32x4 a = {};
            bf16x8 b0 = *(const bf16x8*)&k_lds[(f * 16 + (l & 15)) * 72 + (l >> 4) * 8];
            a = __builtin_amdgcn_mfma_f32_16x16x32_bf16(aq0, b0, a, 0, 0, 0);
            bf16x8 b1 = *(const bf16x8*)&k_lds[(f * 16 + (l & 15)) * 72 + 32 + (l >> 4) * 8];
            a = __builtin_amdgcn_mfma_f32_16x16x32_bf16(aq1, b1, a, 0, 0, 0);
            s[f] = a;
        }
        // softmax (logits are tiny: skip max subtraction), mask keys >= 196
        float rs[4] = {0.f, 0.f, 0.f, 0.f};
#pragma unroll
        for (int f = 0; f < 13; ++f) {
#pragma unroll
            for (int r = 0; r < 4; ++r) {
                float e = __expf(s[f][r]);
                if (f == 12 && (l & 15) >= 4) e = 0.f;
                s[f][r] = e;
                rs[r] += e;
            }
        }
#pragma unroll
        for (int r = 0; r < 4; ++r) {
            float t = rs[r];
            t += __shfl_xor(t, 1);
            t += __shfl_xor(t, 2);
            t += __shfl_xor(t, 4);
            t += __shfl_xor(t, 8);
            rs[r] = __builtin_amdgcn_rcpf(t);   // 1/denom; applied in O epilogue
        }
        // O = P V, streamed through the per-wave P slice
        f32x4 o[4] = {};
#pragma unroll
        for (int kb = 0; kb < 7; ++kb) {
#pragma unroll
            for (int fh = 0; fh < 2; ++fh) {
                int f = kb * 2 + fh;
#pragma unroll
                for (int r = 0; r < 4; ++r) {
                    float pv = 0.f;
                    if (f < 13) pv = s[f][r];
                    pw[((l >> 4) * 4 + r) * 36 + fh * 16 + (l & 15)] = f2bf(pv);
                }
            }
            u16x4 lo = *(const u16x4*)&pw[(l & 15) * 36 + (l >> 4) * 8];
            u16x4 hi = *(const u16x4*)&pw[(l & 15) * 36 + (l >> 4) * 8 + 4];
            union { u16x4 h4[2]; bf16x8 v8; } uu;
            uu.h4[0] = lo; uu.h4[1] = hi;
            bf16x8 pa = uu.v8;
#pragma unroll
            for (int j = 0; j < 4; ++j) {
                bf16x8 bv = *(const bf16x8*)&vT[(j * 16 + (l & 15)) * 232 + kb * 32 + (l >> 4) * 8];
                o[j] = __builtin_amdgcn_mfma_f32_16x16x32_bf16(pa, bv, o[j], 0, 0, 0);
            }
        }
        // store O (h-major col layout), fold in 1/denom
#pragma unroll
        for (int j = 0; j < 4; ++j) {
#pragma unroll
            for (int r = 0; r < 4; ++r) {
                int q = q0 + (l >> 4) * 4 + r;
                if (q < 196)
                    osc[(m_base + q) * 384 + h * 64 + j * 16 + (l & 15)] = f2bf(o[j][r] * rs[r]);
            }
        }
    }
}

extern "C" void kernel_launch(void* const* d_in, const int* in_sizes, int n_in,
                              void* d_out, int out_size, void* d_ws, size_t ws_size,
                              hipStream_t stream) {
    const float* x     = (const float*)d_in[0];
    const float* Wqkv  = (const float*)d_in[1];
    const float* bqkv  = (const float*)d_in[2];
    const float* Wproj = (const float*)d_in[3];
    const float* bproj = (const float*)d_in[4];

    // workspace layout (all bf16/u16):
    //   obf    : M*384      (attention output, proj's A operand)
    //   qkvb   : M*1152
    //   wqkvb  : 1152*384
    //   wprojb : 384*384 (col-permuted)
    const size_t need = ((size_t)M_TOTAL * 384 + (size_t)M_TOTAL * QKV_N
                         + (size_t)QKV_N * K_DIM + (size_t)K_DIM * K_DIM) * 2;
    if (ws_size < need) {
        // diagnostic signature: zeros -> absmax error == ref absmax (0.1138)
        hipMemsetAsync(d_out, 0, (size_t)out_size * 4, stream);
        return;
    }

    u16* obf    = (u16*)d_ws;
    u16* qkvb   = obf + (size_t)M_TOTAL * 384;
    u16* wqkvb  = qkvb + (size_t)M_TOTAL * QKV_N;
    u16* wprojb = wqkvb + (size_t)QKV_N * K_DIM;

    cvt_bf16_kern<<<216, 256, 0, stream>>>(Wqkv, wqkvb, 55296);
    cvt_wproj_kern<<<576, 256, 0, stream>>>(Wproj, wprojb);

    // qkv GEMM reads x (fp32) directly -- A-frags converted in registers
    gemm_kern<QKV_N, true, true, true><<<1568, 256, 0, stream>>>(x, wqkvb, bqkv, qkvb);
    attn_kern<<<3072, 256, 0, stream>>>(qkvb, obf);
    gemm_kern<384, false, false, false><<<1568, 256, 0, stream>>>(obf, wprojb, bproj, (float*)d_out);
}

// Round 7
// 450.942 us; speedup vs baseline: 2.4181x; 2.4181x over previous
//
#include <hip/hip_runtime.h>
#include <cstdint>
#include <cstddef>

typedef unsigned short u16;
typedef __attribute__((ext_vector_type(4))) float f32x4;
typedef __attribute__((ext_vector_type(8))) __bf16 bf16x8;
typedef __attribute__((ext_vector_type(8))) unsigned short u16x8;

#define M_TOTAL 100352   // B*T*N = 8*64*196
#define K_DIM   384
#define QKV_N   1152
#define NHEADS  6
#define NPAT    196
#define SCL     0.125f   // HEAD_DIM^-0.5

__device__ __forceinline__ u16 f2bf(float f) {
    unsigned int u = __builtin_bit_cast(unsigned int, f);
    u += 0x7fffu + ((u >> 16) & 1u);   // RNE
    return (u16)(u >> 16);
}

__device__ __forceinline__ unsigned int pack2(float a, float b) {
    union { __bf16 h[2]; unsigned int u; } p;
    p.h[0] = (__bf16)a; p.h[1] = (__bf16)b;
    return p.u;
}

__device__ __forceinline__ void gload16(const void* g, void* l) {
    __builtin_amdgcn_global_load_lds(
        (const __attribute__((address_space(1))) unsigned int*)g,
        (__attribute__((address_space(3))) unsigned int*)l, 16, 0, 0);
}

// chunked XCD swizzle; requires gridDim.x % 8 == 0 (true for all launches here)
__device__ __forceinline__ int xcd_swz(int bid, int per_xcd) {
    return (bid & 7) * per_xcd + (bid >> 3);
}

// ---------------- fp32 -> bf16 convert (8 elems/thread) ----------------
__global__ void cvt_bf16_kern(const float* __restrict__ in, u16* __restrict__ out, int n8) {
    int i = blockIdx.x * 256 + threadIdx.x;
    if (i >= n8) return;
    const float4* p = (const float4*)in + (size_t)i * 2;
    float4 a = p[0], b = p[1];
    u16x8 o;
    o[0]=f2bf(a.x); o[1]=f2bf(a.y); o[2]=f2bf(a.z); o[3]=f2bf(a.w);
    o[4]=f2bf(b.x); o[5]=f2bf(b.y); o[6]=f2bf(b.z); o[7]=f2bf(b.w);
    *((u16x8*)out + i) = o;
}

// W_proj convert with column permute: out[o][h*64+d] = W[o][d*6+h]
__global__ void cvt_wproj_kern(const float* __restrict__ in, u16* __restrict__ out) {
    int i = blockIdx.x * 256 + threadIdx.x;   // i = o*384 + c''
    int o = i / 384;
    int c = i - o * 384;        // NOTE: 384 is not pow2 — cannot use i & 383
    int d = c & 63, h = c >> 6; // c'' = h*64 + d (64 IS pow2)
    out[i] = f2bf(in[(size_t)o * 384 + d * 6 + h]);
}

// ---------------- GEMM: C[M,NOUT] = A[M,384] * Bw[NOUT,384]^T + bias ----------------
// Round-3 verified structure (best measured: 573 TF, conflicts 0). T2 XOR-swizzle
// both LDS tiles (rule 21: linear gload_lds dest + inverse-swizzled global source
// + swizzled ds_read address).
template<int NOUT, bool BF16OUT, bool QSCALE>
__global__ __launch_bounds__(256, 2) void gemm_kern(
        const u16* __restrict__ A, const u16* __restrict__ Bw,
        const float* __restrict__ bias, void* __restrict__ outp) {
    constexpr int NB = NOUT / 128;
    constexpr int PER_XCD = (M_TOTAL / 128) * NB / 8;
    __shared__ u16 As[128 * 64];
    __shared__ u16 Bs[128 * 64];
    int wg = xcd_swz(blockIdx.x, PER_XCD);
    int bm = wg / NB, bn = wg % NB;
    int tid = threadIdx.x;
    int l = tid & 63, w = tid >> 6;
    int wr = w >> 1, wc = w & 1;
    f32x4 acc[4][4] = {};
    const u16* Ag = A + (size_t)bm * 128 * K_DIM;
    const u16* Bg = Bw + (size_t)bn * 128 * K_DIM;

    for (int ks = 0; ks < 6; ++ks) {
#pragma unroll
        for (int i = 0; i < 4; ++i) {
            int c = i * 256 + tid;
            int row = c >> 3, cc = c & 7;
            int scc = cc ^ (row & 7);   // inverse-swizzled source chunk
            gload16(Ag + (size_t)row * K_DIM + ks * 64 + scc * 8, (u16*)As + c * 8);
            gload16(Bg + (size_t)row * K_DIM + ks * 64 + scc * 8, (u16*)Bs + c * 8);
        }
        __syncthreads();
#pragma unroll
        for (int kk = 0; kk < 2; ++kk) {
            bf16x8 af[4], bfr[4];
            int ccr = kk * 4 + (l >> 4);
#pragma unroll
            for (int m = 0; m < 4; ++m) {
                int ar = wr * 64 + m * 16 + (l & 15);
                af[m] = *(const bf16x8*)&As[ar * 64 + ((ccr ^ (ar & 7)) << 3)];
            }
#pragma unroll
            for (int n = 0; n < 4; ++n) {
                int br = wc * 64 + n * 16 + (l & 15);
                bfr[n] = *(const bf16x8*)&Bs[br * 64 + ((ccr ^ (br & 7)) << 3)];
            }
#pragma unroll
            for (int m = 0; m < 4; ++m)
#pragma unroll
                for (int n = 0; n < 4; ++n)
                    acc[m][n] = __builtin_amdgcn_mfma_f32_16x16x32_bf16(af[m], bfr[n], acc[m][n], 0, 0, 0);
        }
        __syncthreads();
    }
    // epilogue
#pragma unroll
    for (int n = 0; n < 4; ++n) {
        int col = bn * 128 + wc * 64 + n * 16 + (l & 15);
        float bv = bias[col];
#pragma unroll
        for (int m = 0; m < 4; ++m) {
            int row0 = bm * 128 + wr * 64 + m * 16 + (l >> 4) * 4;
#pragma unroll
            for (int r = 0; r < 4; ++r) {
                float v = acc[m][n][r] + bv;
                if constexpr (QSCALE) { if (col < 384) v *= SCL; }
                if constexpr (BF16OUT)
                    ((u16*)outp)[(size_t)(row0 + r) * NOUT + col] = f2bf(v);
                else
                    ((float*)outp)[(size_t)(row0 + r) * NOUT + col] = v;
            }
        }
    }
}

// ---------------- attention per (b,t,h): 196x196 over head_dim 64 ----------------
// Swapped QK^T (S^T = mfma(K,Q)) + PERMUTED K-row staging so each lane's S
// C-fragment slots are exactly its PV A-fragment keys -> P never leaves the
// lane (zero shuffles, zero LDS round-trip, all-static reg indexing).
//   key n staged at LDS row rho(n) = (2*(n>>5) + ((n>>2)&1))*16 + ((n>>3)&3)*4 + (n&3)
//   => lane (lg,lr), frag f holds S[q=lr][key = 32*(f>>1) + lg*8 + 4*(f&1) + r].
// Virtual frag 13 (keys 196-199,204-207,212-215,220-223) is identically zero:
// never computed. Mask: f==12 && lg>0 covers keys 200-219 >= 196.
// 1/denom folded into the P bf16 pack; epilogue stores bare o.
__global__ __launch_bounds__(256, 2) void attn_kern(const u16* __restrict__ qkv,
                                                    u16* __restrict__ osc) {
    __shared__ u16 k_lds[224 * 72];   // [perm-row][d], stride 72 (16B-aligned rows)
    __shared__ u16 vT[64 * 232];      // [d][key], natural key order, zero-padded

    int wg = xcd_swz(blockIdx.x, 384);
    int h = wg % NHEADS;
    int bt = wg / NHEADS;
    size_t m_base = (size_t)bt * NPAT;
    int tid = threadIdx.x, l = tid & 63, w = tid >> 6;
    int lr = l & 15, lg = l >> 4;

    // stage K rows 0..223 (zeros for key >= 196) at permuted rows. 8 lanes/row.
    {
        int d0 = (tid & 7) * 8;
#pragma unroll
        for (int it = 0; it < 7; ++it) {
            int n = it * 32 + (tid >> 3);           // 7*32 = 224 rows exactly
            u16x8 val = {};
            if (n < 196)
                val = *(const u16x8*)(qkv + (m_base + n) * QKV_N + 384 + h * 64 + d0);
            int pr = (2 * (n >> 5) + ((n >> 2) & 1)) * 16 + ((n >> 3) & 3) * 4 + (n & 3);
            *(u16x8*)&k_lds[pr * 72 + d0] = val;
        }
    }
    // stage V transposed: wave w owns d rows w*16..w*16+15; lane = key row.
    {
        int d0 = w * 16;
#pragma unroll
        for (int it = 0; it < 4; ++it) {
            int n = it * 64 + l;
            if (n < 232) {
                u16x8 v0 = {}, v1 = {};
                if (n < 196) {
                    const u16* src = qkv + (m_base + n) * QKV_N + 768 + h * 64 + d0;
                    v0 = *(const u16x8*)src;
                    v1 = *(const u16x8*)(src + 8);
                }
#pragma unroll
                for (int j = 0; j < 8; ++j) {
                    vT[(d0 + j) * 232 + n] = v0[j];
                    vT[(d0 + 8 + j) * 232 + n] = v1[j];
                }
            }
        }
    }
    __syncthreads();

    for (int qt = w; qt < 13; qt += 4) {
        int q0 = qt * 16;
        // Q as B-operand, straight from global (q pre-scaled in qkv epilogue)
        int qrow = q0 + lr; if (qrow > 195) qrow = 195;
        const u16* qsrc = qkv + (m_base + qrow) * QKV_N + h * 64 + lg * 8;
        bf16x8 bq0 = *(const bf16x8*)qsrc;
        bf16x8 bq1 = *(const bf16x8*)(qsrc + 32);

        // S^T = K Q^T : lane holds S[q=lr][perm-keys], 13 computed frags
        f32x4 s[13];
#pragma unroll
        for (int f = 0; f < 13; ++f) {
            f32x4 a = {};
            bf16x8 k0 = *(const bf16x8*)&k_lds[(f * 16 + lr) * 72 + lg * 8];
            a = __builtin_amdgcn_mfma_f32_16x16x32_bf16(k0, bq0, a, 0, 0, 0);
            bf16x8 k1 = *(const bf16x8*)&k_lds[(f * 16 + lr) * 72 + 32 + lg * 8];
            a = __builtin_amdgcn_mfma_f32_16x16x32_bf16(k1, bq1, a, 0, 0, 0);
            s[f] = a;
        }
        // softmax over the lane's row (logits tiny: no max subtraction)
        float sum = 0.f;
#pragma unroll
        for (int f = 0; f < 13; ++f)
#pragma unroll
            for (int r = 0; r < 4; ++r) {
                float e = __expf(s[f][r]);
                if (f == 12 && lg > 0) e = 0.f;   // perm-keys 200..219 masked
                s[f][r] = e;
                sum += e;
            }
        sum += __shfl_xor(sum, 16);
        sum += __shfl_xor(sum, 32);
        float rs = __builtin_amdgcn_rcpf(sum);

        // pack P*rs to bf16 pairs, lane-local; frag 13 is zero
        unsigned int pk0[14], pk1[14];
#pragma unroll
        for (int f = 0; f < 13; ++f) {
            pk0[f] = pack2(s[f][0] * rs, s[f][1] * rs);
            pk1[f] = pack2(s[f][2] * rs, s[f][3] * rs);
        }
        pk0[13] = 0u; pk1[13] = 0u;

        // O = P V : A-frag assembled from the lane's own packs (static idx)
        f32x4 o[4] = {};
#pragma unroll
        for (int kb = 0; kb < 7; ++kb) {
            union { unsigned int u[4]; bf16x8 v; } pa;
            pa.u[0] = pk0[2 * kb];     pa.u[1] = pk1[2 * kb];
            pa.u[2] = pk0[2 * kb + 1]; pa.u[3] = pk1[2 * kb + 1];
#pragma unroll
            for (int j = 0; j < 4; ++j) {
                bf16x8 bv = *(const bf16x8*)&vT[(j * 16 + lr) * 232 + kb * 32 + lg * 8];
                o[j] = __builtin_amdgcn_mfma_f32_16x16x32_bf16(pa.v, bv, o[j], 0, 0, 0);
            }
        }
        // store O (h-major col layout; denom already folded into P)
#pragma unroll
        for (int j = 0; j < 4; ++j) {
#pragma unroll
            for (int r = 0; r < 4; ++r) {
                int q = q0 + lg * 4 + r;
                if (q < 196)
                    osc[(m_base + q) * 384 + h * 64 + j * 16 + lr] = f2bf(o[j][r]);
            }
        }
    }
}

extern "C" void kernel_launch(void* const* d_in, const int* in_sizes, int n_in,
                              void* d_out, int out_size, void* d_ws, size_t ws_size,
                              hipStream_t stream) {
    const float* x     = (const float*)d_in[0];
    const float* Wqkv  = (const float*)d_in[1];
    const float* bqkv  = (const float*)d_in[2];
    const float* Wproj = (const float*)d_in[3];
    const float* bproj = (const float*)d_in[4];

    // workspace layout (all bf16/u16):
    //   xbf    : M*384      (x in bf16; reused as attention output)
    //   qkvb   : M*1152
    //   wqkvb  : 1152*384
    //   wprojb : 384*384 (col-permuted)
    const size_t need = ((size_t)M_TOTAL * 384 + (size_t)M_TOTAL * QKV_N
                         + (size_t)QKV_N * K_DIM + (size_t)K_DIM * K_DIM) * 2;
    if (ws_size < need) {
        hipMemsetAsync(d_out, 0, (size_t)out_size * 4, stream);
        return;
    }

    u16* xbf    = (u16*)d_ws;
    u16* qkvb   = xbf + (size_t)M_TOTAL * 384;
    u16* wqkvb  = qkvb + (size_t)M_TOTAL * QKV_N;
    u16* wprojb = wqkvb + (size_t)QKV_N * K_DIM;

    cvt_bf16_kern<<<18816, 256, 0, stream>>>(x, xbf, 4816896);
    cvt_bf16_kern<<<216, 256, 0, stream>>>(Wqkv, wqkvb, 55296);
    cvt_wproj_kern<<<576, 256, 0, stream>>>(Wproj, wprojb);

    gemm_kern<QKV_N, true, true><<<7056, 256, 0, stream>>>(xbf, wqkvb, bqkv, qkvb);
    attn_kern<<<3072, 256, 0, stream>>>(qkvb, xbf);
    gemm_kern<384, false, false><<<2352, 256, 0, stream>>>(xbf, wprojb, bproj, (float*)d_out);
}

// Round 8
// 325.327 us; speedup vs baseline: 3.3518x; 1.3861x over previous
//
#include <hip/hip_runtime.h>
#include <cstdint>
#include <cstddef>

typedef unsigned short u16;
typedef __attribute__((ext_vector_type(4))) float f32x4;
typedef __attribute__((ext_vector_type(8))) __bf16 bf16x8;
typedef __attribute__((ext_vector_type(8))) unsigned short u16x8;

#define M_TOTAL 100352   // B*T*N = 8*64*196
#define K_DIM   384
#define QKV_N   1152
#define NHEADS  6
#define NPAT    196
#define SCL     0.125f   // HEAD_DIM^-0.5

__device__ __forceinline__ u16 f2bf(float f) {
    unsigned int u = __builtin_bit_cast(unsigned int, f);
    u += 0x7fffu + ((u >> 16) & 1u);   // RNE
    return (u16)(u >> 16);
}

__device__ __forceinline__ unsigned int pack2(float a, float b) {
    union { __bf16 h[2]; unsigned int u; } p;
    p.h[0] = (__bf16)a; p.h[1] = (__bf16)b;
    return p.u;
}

__device__ __forceinline__ void gload16(const void* g, void* l) {
    __builtin_amdgcn_global_load_lds(
        (const __attribute__((address_space(1))) unsigned int*)g,
        (__attribute__((address_space(3))) unsigned int*)l, 16, 0, 0);
}

// chunked XCD swizzle; requires gridDim.x % 8 == 0 (true for all launches here)
__device__ __forceinline__ int xcd_swz(int bid, int per_xcd) {
    return (bid & 7) * per_xcd + (bid >> 3);
}

// ---------------- fp32 -> bf16 convert (8 elems/thread) ----------------
__global__ void cvt_bf16_kern(const float* __restrict__ in, u16* __restrict__ out, int n8) {
    int i = blockIdx.x * 256 + threadIdx.x;
    if (i >= n8) return;
    const float4* p = (const float4*)in + (size_t)i * 2;
    float4 a = p[0], b = p[1];
    u16x8 o;
    o[0]=f2bf(a.x); o[1]=f2bf(a.y); o[2]=f2bf(a.z); o[3]=f2bf(a.w);
    o[4]=f2bf(b.x); o[5]=f2bf(b.y); o[6]=f2bf(b.z); o[7]=f2bf(b.w);
    *((u16x8*)out + i) = o;
}

// W_proj convert with column permute: out[o][h*64+d] = W[o][d*6+h]
__global__ void cvt_wproj_kern(const float* __restrict__ in, u16* __restrict__ out) {
    int i = blockIdx.x * 256 + threadIdx.x;   // i = o*384 + c''
    int o = i / 384;
    int c = i - o * 384;        // NOTE: 384 is not pow2 — cannot use i & 383
    int d = c & 63, h = c >> 6; // c'' = h*64 + d (64 IS pow2)
    out[i] = f2bf(in[(size_t)o * 384 + d * 6 + h]);
}

// ---------------- GEMM: C[M,NOUT] = A[M,384] * Bw[NOUT,384]^T + bias ----------------
// Round-3 verified structure (best measured: 573 TF, conflicts 0). T2 XOR-swizzle
// both LDS tiles (rule 21: linear gload_lds dest + inverse-swizzled global source
// + swizzled ds_read address).
template<int NOUT, bool BF16OUT, bool QSCALE>
__global__ __launch_bounds__(256, 2) void gemm_kern(
        const u16* __restrict__ A, const u16* __restrict__ Bw,
        const float* __restrict__ bias, void* __restrict__ outp) {
    constexpr int NB = NOUT / 128;
    constexpr int PER_XCD = (M_TOTAL / 128) * NB / 8;
    __shared__ u16 As[128 * 64];
    __shared__ u16 Bs[128 * 64];
    int wg = xcd_swz(blockIdx.x, PER_XCD);
    int bm = wg / NB, bn = wg % NB;
    int tid = threadIdx.x;
    int l = tid & 63, w = tid >> 6;
    int wr = w >> 1, wc = w & 1;
    f32x4 acc[4][4] = {};
    const u16* Ag = A + (size_t)bm * 128 * K_DIM;
    const u16* Bg = Bw + (size_t)bn * 128 * K_DIM;

    for (int ks = 0; ks < 6; ++ks) {
#pragma unroll
        for (int i = 0; i < 4; ++i) {
            int c = i * 256 + tid;
            int row = c >> 3, cc = c & 7;
            int scc = cc ^ (row & 7);   // inverse-swizzled source chunk
            gload16(Ag + (size_t)row * K_DIM + ks * 64 + scc * 8, (u16*)As + c * 8);
            gload16(Bg + (size_t)row * K_DIM + ks * 64 + scc * 8, (u16*)Bs + c * 8);
        }
        __syncthreads();
#pragma unroll
        for (int kk = 0; kk < 2; ++kk) {
            bf16x8 af[4], bfr[4];
            int ccr = kk * 4 + (l >> 4);
#pragma unroll
            for (int m = 0; m < 4; ++m) {
                int ar = wr * 64 + m * 16 + (l & 15);
                af[m] = *(const bf16x8*)&As[ar * 64 + ((ccr ^ (ar & 7)) << 3)];
            }
#pragma unroll
            for (int n = 0; n < 4; ++n) {
                int br = wc * 64 + n * 16 + (l & 15);
                bfr[n] = *(const bf16x8*)&Bs[br * 64 + ((ccr ^ (br & 7)) << 3)];
            }
#pragma unroll
            for (int m = 0; m < 4; ++m)
#pragma unroll
                for (int n = 0; n < 4; ++n)
                    acc[m][n] = __builtin_amdgcn_mfma_f32_16x16x32_bf16(af[m], bfr[n], acc[m][n], 0, 0, 0);
        }
        __syncthreads();
    }
    // epilogue
#pragma unroll
    for (int n = 0; n < 4; ++n) {
        int col = bn * 128 + wc * 64 + n * 16 + (l & 15);
        float bv = bias[col];
#pragma unroll
        for (int m = 0; m < 4; ++m) {
            int row0 = bm * 128 + wr * 64 + m * 16 + (l >> 4) * 4;
#pragma unroll
            for (int r = 0; r < 4; ++r) {
                float v = acc[m][n][r] + bv;
                if constexpr (QSCALE) { if (col < 384) v *= SCL; }
                if constexpr (BF16OUT)
                    ((u16*)outp)[(size_t)(row0 + r) * NOUT + col] = f2bf(v);
                else
                    ((float*)outp)[(size_t)(row0 + r) * NOUT + col] = v;
            }
        }
    }
}

// ---------------- attention per (b,t,h): 196x196 over head_dim 64 ----------------
// Swapped QK^T (S^T = mfma(K,Q)) + PERMUTED K-row staging: lane's S C-frag slots
// are exactly its PV A-frag keys -> P never leaves the lane (verified round 7).
//   key n at LDS row rho(n) = (2*(n>>5)+((n>>2)&1))*16 + ((n>>3)&3)*4 + (n&3)
//   lane (lg,lr) frag f holds S[q=lr][key = 32*(f>>1) + lg*8 + 4*(f&1) + r].
// Round-8 change: 512 threads / 8 waves, __launch_bounds__(512,4) to force
// VGPR<=128 -> 2 blocks/CU * 8 waves = 16 waves/CU (2x round-7 occupancy; the
// round-7 profile was latency-bound: Mfma 6%, VALU 14%, HBM 27%, all idle).
__device__ __forceinline__ void attn_qt(
        const u16* __restrict__ k_lds, const u16* __restrict__ vT,
        u16* __restrict__ osc, size_t m_base, int h, int lr, int lg,
        int qt, bf16x8 bq0, bf16x8 bq1) {
    // S^T = K Q^T : 13 computed frags (virtual frag 13 is identically zero)
    f32x4 s[13];
    __builtin_amdgcn_s_setprio(1);
#pragma unroll
    for (int f = 0; f < 13; ++f) {
        f32x4 a = {};
        bf16x8 k0 = *(const bf16x8*)&k_lds[(f * 16 + lr) * 72 + lg * 8];
        a = __builtin_amdgcn_mfma_f32_16x16x32_bf16(k0, bq0, a, 0, 0, 0);
        bf16x8 k1 = *(const bf16x8*)&k_lds[(f * 16 + lr) * 72 + 32 + lg * 8];
        a = __builtin_amdgcn_mfma_f32_16x16x32_bf16(k1, bq1, a, 0, 0, 0);
        s[f] = a;
    }
    __builtin_amdgcn_s_setprio(0);
    // softmax over the lane's row (logits tiny: no max subtraction); 4 ILP chains
    float p0 = 0.f, p1 = 0.f, p2 = 0.f, p3 = 0.f;
#pragma unroll
    for (int f = 0; f < 13; ++f) {
        float e0 = __expf(s[f][0]), e1 = __expf(s[f][1]);
        float e2 = __expf(s[f][2]), e3 = __expf(s[f][3]);
        if (f == 12 && lg > 0) { e0 = 0.f; e1 = 0.f; e2 = 0.f; e3 = 0.f; }
        s[f][0] = e0; s[f][1] = e1; s[f][2] = e2; s[f][3] = e3;
        p0 += e0; p1 += e1; p2 += e2; p3 += e3;
    }
    float sum = (p0 + p1) + (p2 + p3);
    sum += __shfl_xor(sum, 16);
    sum += __shfl_xor(sum, 32);
    float rs = __builtin_amdgcn_rcpf(sum);

    // pack P*rs to bf16 pairs, lane-local; frag 13 is zero
    unsigned int pk0[14], pk1[14];
#pragma unroll
    for (int f = 0; f < 13; ++f) {
        pk0[f] = pack2(s[f][0] * rs, s[f][1] * rs);
        pk1[f] = pack2(s[f][2] * rs, s[f][3] * rs);
    }
    pk0[13] = 0u; pk1[13] = 0u;

    // O = P V : A-frag assembled from the lane's own packs (static idx)
    f32x4 o[4] = {};
    __builtin_amdgcn_s_setprio(1);
#pragma unroll
    for (int kb = 0; kb < 7; ++kb) {
        union { unsigned int u[4]; bf16x8 v; } pa;
        pa.u[0] = pk0[2 * kb];     pa.u[1] = pk1[2 * kb];
        pa.u[2] = pk0[2 * kb + 1]; pa.u[3] = pk1[2 * kb + 1];
#pragma unroll
        for (int j = 0; j < 4; ++j) {
            bf16x8 bv = *(const bf16x8*)&vT[(j * 16 + lr) * 232 + kb * 32 + lg * 8];
            o[j] = __builtin_amdgcn_mfma_f32_16x16x32_bf16(pa.v, bv, o[j], 0, 0, 0);
        }
    }
    __builtin_amdgcn_s_setprio(0);
    // store O (h-major col layout; denom already folded into P)
    int q0 = qt * 16;
#pragma unroll
    for (int j = 0; j < 4; ++j) {
#pragma unroll
        for (int r = 0; r < 4; ++r) {
            int q = q0 + lg * 4 + r;
            if (q < 196)
                osc[(m_base + q) * 384 + h * 64 + j * 16 + lr] = f2bf(o[j][r]);
        }
    }
}

__global__ __launch_bounds__(512, 4) void attn_kern(const u16* __restrict__ qkv,
                                                    u16* __restrict__ osc) {
    __shared__ u16 k_lds[224 * 72];   // [perm-row][d], stride 72 (16B-aligned rows)
    __shared__ u16 vT[64 * 232];      // [d][key], natural key order, zero-padded

    int wg = xcd_swz(blockIdx.x, 384);
    int h = wg % NHEADS;
    int bt = wg / NHEADS;
    size_t m_base = (size_t)bt * NPAT;
    int tid = threadIdx.x, l = tid & 63, w = tid >> 6;   // w in 0..7
    int lr = l & 15, lg = l >> 4;

    // prefetch this wave's first Q tile (issue-early: overlaps staging latency)
    bf16x8 q00, q01;
    {
        int qrow = w * 16 + lr; if (qrow > 195) qrow = 195;
        const u16* qs = qkv + (m_base + qrow) * QKV_N + h * 64 + lg * 8;
        q00 = *(const bf16x8*)qs;
        q01 = *(const bf16x8*)(qs + 32);
    }

    // stage K rows 0..223 (zeros for key >= 196) at permuted rows. 8 lanes/row.
    {
        int d0 = (tid & 7) * 8;
#pragma unroll
        for (int it = 0; it < 4; ++it) {
            int n = it * 64 + (tid >> 3);
            if (n < 224) {
                u16x8 val = {};
                if (n < 196)
                    val = *(const u16x8*)(qkv + (m_base + n) * QKV_N + 384 + h * 64 + d0);
                int pr = (2 * (n >> 5) + ((n >> 2) & 1)) * 16 + ((n >> 3) & 3) * 4 + (n & 3);
                *(u16x8*)&k_lds[pr * 72 + d0] = val;
            }
        }
    }
    // stage V transposed: wave w owns d rows w*8..w*8+7; lane = key row.
    {
        int d0 = w * 8;
#pragma unroll
        for (int it = 0; it < 4; ++it) {
            int n = it * 64 + l;
            if (n < 232) {
                u16x8 v0 = {};
                if (n < 196)
                    v0 = *(const u16x8*)(qkv + (m_base + n) * QKV_N + 768 + h * 64 + d0);
#pragma unroll
                for (int j = 0; j < 8; ++j)
                    vT[(d0 + j) * 232 + n] = v0[j];
            }
        }
    }
    __syncthreads();

    // qt = w, then w+8 (waves 5..7 have only one tile)
    attn_qt(k_lds, vT, osc, m_base, h, lr, lg, w, q00, q01);
    int qt1 = w + 8;
    if (qt1 < 13) {
        int qrow = qt1 * 16 + lr; if (qrow > 195) qrow = 195;
        const u16* qs = qkv + (m_base + qrow) * QKV_N + h * 64 + lg * 8;
        attn_qt(k_lds, vT, osc, m_base, h, lr, lg, qt1,
                *(const bf16x8*)qs, *(const bf16x8*)(qs + 32));
    }
}

extern "C" void kernel_launch(void* const* d_in, const int* in_sizes, int n_in,
                              void* d_out, int out_size, void* d_ws, size_t ws_size,
                              hipStream_t stream) {
    const float* x     = (const float*)d_in[0];
    const float* Wqkv  = (const float*)d_in[1];
    const float* bqkv  = (const float*)d_in[2];
    const float* Wproj = (const float*)d_in[3];
    const float* bproj = (const float*)d_in[4];

    // workspace layout (all bf16/u16):
    //   xbf    : M*384      (x in bf16; reused as attention output)
    //   qkvb   : M*1152
    //   wqkvb  : 1152*384
    //   wprojb : 384*384 (col-permuted)
    const size_t need = ((size_t)M_TOTAL * 384 + (size_t)M_TOTAL * QKV_N
                         + (size_t)QKV_N * K_DIM + (size_t)K_DIM * K_DIM) * 2;
    if (ws_size < need) {
        hipMemsetAsync(d_out, 0, (size_t)out_size * 4, stream);
        return;
    }

    u16* xbf    = (u16*)d_ws;
    u16* qkvb   = xbf + (size_t)M_TOTAL * 384;
    u16* wqkvb  = qkvb + (size_t)M_TOTAL * QKV_N;
    u16* wprojb = wqkvb + (size_t)QKV_N * K_DIM;

    cvt_bf16_kern<<<18816, 256, 0, stream>>>(x, xbf, 4816896);
    cvt_bf16_kern<<<216, 256, 0, stream>>>(Wqkv, wqkvb, 55296);
    cvt_wproj_kern<<<576, 256, 0, stream>>>(Wproj, wprojb);

    gemm_kern<QKV_N, true, true><<<7056, 256, 0, stream>>>(xbf, wqkvb, bqkv, qkvb);
    attn_kern<<<3072, 512, 0, stream>>>(qkvb, xbf);
    gemm_kern<384, false, false><<<2352, 256, 0, stream>>>(xbf, wprojb, bproj, (float*)d_out);
}